// Round 11
// baseline (359.539 us; speedup 1.0000x reference)
//
#include <hip/hip_runtime.h>

#define NN 131072   // nodes
#define NE 524288   // edges
#define NG 4096     // graphs
#define ECAP 1024   // max edges staged in LDS per 64-node block (mean 256)

typedef __attribute__((ext_vector_type(8))) short bfx8;
typedef __attribute__((ext_vector_type(4))) float f32x4;

static __device__ __forceinline__ ushort f2bf(float f) {
    union { float f; unsigned u; } v; v.f = f;
    unsigned r = (v.u + 0x7fff + ((v.u >> 16) & 1)) >> 16;   // RNE
    return (ushort)r;
}
static __device__ __forceinline__ float bf2f(short s) {
    union { unsigned u; float f; } v;
    v.u = ((unsigned)(ushort)s) << 16;
    return v.f;
}

// ---------------- preprocessing: degree, dis, CSR ----------------

__global__ void k_count(const int* __restrict__ dst, int* __restrict__ counts) {
    int e = blockIdx.x * blockDim.x + threadIdx.x;
    if (e < NE) atomicAdd(&counts[dst[e]], 1);
}

__global__ void k_dis(const int* __restrict__ counts, float* __restrict__ dis) {
    int i = blockIdx.x * blockDim.x + threadIdx.x;
    if (i < NN) dis[i] = rsqrtf((float)(counts[i] + 1));  // +1 self-loop
}

__global__ void k_scanA(const int* __restrict__ in, int* __restrict__ out, int* __restrict__ bsum) {
    __shared__ int s[256];
    int t = threadIdx.x;
    int i = blockIdx.x * 256 + t;
    int v = in[i];
    s[t] = v;
    __syncthreads();
    for (int off = 1; off < 256; off <<= 1) {
        int x = (t >= off) ? s[t - off] : 0;
        __syncthreads();
        s[t] += x;
        __syncthreads();
    }
    out[i] = s[t] - v;
    if (t == 255) bsum[blockIdx.x] = s[t];
}

__global__ void k_scanB(int* __restrict__ bsum) {
    __shared__ int s[512];
    int t = threadIdx.x;
    int v = bsum[t];
    s[t] = v;
    __syncthreads();
    for (int off = 1; off < 512; off <<= 1) {
        int x = (t >= off) ? s[t - off] : 0;
        __syncthreads();
        s[t] += x;
        __syncthreads();
    }
    bsum[t] = s[t] - v;
}

__global__ void k_scanC(int* __restrict__ rowstart, const int* __restrict__ bsum) {
    int t = threadIdx.x;
    int i = blockIdx.x * 256 + t;
    rowstart[i] += bsum[blockIdx.x];
    if (i == 0) rowstart[NN] = NE;
}

__global__ void k_fill(const int* __restrict__ src, const int* __restrict__ dst,
                       const int* __restrict__ rowstart, int* __restrict__ cursor,
                       const float* __restrict__ dis,
                       int* __restrict__ col, float* __restrict__ wgt) {
    int e = blockIdx.x * blockDim.x + threadIdx.x;
    if (e >= NE) return;
    int s = src[e], d = dst[e];
    int pos = rowstart[d] + atomicAdd(&cursor[d], 1);
    col[pos] = s;
    wgt[pos] = dis[s] * dis[d];
}

// W [CI][CO] fp32 -> WT [CO][KP] bf16 (transposed, zero-padded K)
template<int CI, int CO, int KP>
__global__ void k_prepW(const float* __restrict__ W, ushort* __restrict__ WT) {
    int idx = blockIdx.x * 256 + threadIdx.x;
    if (idx >= CO * KP) return;
    int n = idx / KP, k = idx - n * KP;
    float v = (k < CI) ? W[k * CO + n] : 0.0f;
    WT[idx] = f2bf(v);
}

// x [NN][78] fp32 -> xb [NN][96] bf16 zero-padded
__global__ void k_prepX(const float* __restrict__ x, ushort* __restrict__ xb) {
    int idx = blockIdx.x * 256 + threadIdx.x;   // exact NN*96
    int i = idx / 96, c = idx - i * 96;
    xb[idx] = (c < 78) ? f2bf(x[i * 78 + c]) : (ushort)0;
}

// ---------------- fused layer: gather-agg into LDS, then MFMA GEMM ----------------
// Phase 0: stage rowstart[65] + block's edge lists (col,wgt) into LDS (coalesced).
// Phase 1: unit = (row, 64B group of 4 chunks): aggregate 32 channels in registers,
//          gathers are full aligned 64B lines; edge list read from LDS.
// Phase 2: panel-loop MFMA, B direct from L2, no in-loop barriers.

template<int KP, int LCH, int CO, int CPO, bool POOL>
__global__ __launch_bounds__(256)
void k_fused(const ushort* __restrict__ hin, const int* __restrict__ rowstart,
             const int* __restrict__ col, const float* __restrict__ wgt,
             const float* __restrict__ dis,
             const ushort* __restrict__ BT, const float* __restrict__ bias,
             const int* __restrict__ batch,
             ushort* __restrict__ hout, float* __restrict__ pooled) {
    constexpr int NCH = KP / 8;           // 16B chunks per row
    constexpr int NG4 = NCH / 4;          // 64B groups per row
    constexpr int LP  = LCH * 8;          // LDS row pitch in bf16 elems
    constexpr int NP  = (CO + 63) / 64;   // 64-col panels
    __shared__ ushort sA[64 * LP];
    __shared__ int   sRS[65];
    __shared__ int   sCol[ECAP];
    __shared__ float sWgt[ECAP];

    const int tid  = threadIdx.x;
    const int row0 = blockIdx.x * 64;

    // ---- phase 0: stage rowstarts + edge lists ----
    if (tid < 65) sRS[tid] = rowstart[row0 + tid];
    __syncthreads();
    const int base  = sRS[0];
    const int total = sRS[64] - base;
    const bool inLDS = (total <= ECAP);
    if (inLDS) {
        for (int e = tid; e < total; e += 256) {
            sCol[e] = col[base + e];
            sWgt[e] = wgt[base + e];
        }
    }
    __syncthreads();

    // ---- phase 1: gather-aggregate 64B groups into sA ----
    for (int id = tid; id < 64 * NG4; id += 256) {
        int r = id / NG4, g = id - r * NG4;
        int i = row0 + r;
        const ushort* hrow = hin + (size_t)i * KP + g * 32;

        float acc[32];
        {
            float dd = dis[i]; dd *= dd;
            bfx8 s0 = *(const bfx8*)(hrow);
            bfx8 s1 = *(const bfx8*)(hrow + 8);
            bfx8 s2 = *(const bfx8*)(hrow + 16);
            bfx8 s3 = *(const bfx8*)(hrow + 24);
            #pragma unroll
            for (int k = 0; k < 8; ++k) {
                acc[k]      = dd * bf2f(s0[k]);
                acc[8 + k]  = dd * bf2f(s1[k]);
                acc[16 + k] = dd * bf2f(s2[k]);
                acc[24 + k] = dd * bf2f(s3[k]);
            }
        }
        const int j0 = sRS[r] - base, j1 = sRS[r + 1] - base;

        auto edges = [&](const auto* cp, const auto* wp) {
            int j = j0;
            for (; j + 2 <= j1; j += 2) {
                int c0 = cp[j], c1 = cp[j + 1];
                float w0 = wp[j], w1 = wp[j + 1];
                const ushort* g0p = hin + (size_t)c0 * KP + g * 32;
                const ushort* g1p = hin + (size_t)c1 * KP + g * 32;
                bfx8 a0 = *(const bfx8*)(g0p);
                bfx8 a1 = *(const bfx8*)(g0p + 8);
                bfx8 a2 = *(const bfx8*)(g0p + 16);
                bfx8 a3 = *(const bfx8*)(g0p + 24);
                bfx8 b0 = *(const bfx8*)(g1p);
                bfx8 b1 = *(const bfx8*)(g1p + 8);
                bfx8 b2 = *(const bfx8*)(g1p + 16);
                bfx8 b3 = *(const bfx8*)(g1p + 24);
                #pragma unroll
                for (int k = 0; k < 8; ++k) {
                    acc[k]      = fmaf(w0, bf2f(a0[k]), acc[k]);
                    acc[8 + k]  = fmaf(w0, bf2f(a1[k]), acc[8 + k]);
                    acc[16 + k] = fmaf(w0, bf2f(a2[k]), acc[16 + k]);
                    acc[24 + k] = fmaf(w0, bf2f(a3[k]), acc[24 + k]);
                }
                #pragma unroll
                for (int k = 0; k < 8; ++k) {
                    acc[k]      = fmaf(w1, bf2f(b0[k]), acc[k]);
                    acc[8 + k]  = fmaf(w1, bf2f(b1[k]), acc[8 + k]);
                    acc[16 + k] = fmaf(w1, bf2f(b2[k]), acc[16 + k]);
                    acc[24 + k] = fmaf(w1, bf2f(b3[k]), acc[24 + k]);
                }
            }
            for (; j < j1; ++j) {
                int c = cp[j];
                float w = wp[j];
                const ushort* gp = hin + (size_t)c * KP + g * 32;
                bfx8 a0 = *(const bfx8*)(gp);
                bfx8 a1 = *(const bfx8*)(gp + 8);
                bfx8 a2 = *(const bfx8*)(gp + 16);
                bfx8 a3 = *(const bfx8*)(gp + 24);
                #pragma unroll
                for (int k = 0; k < 8; ++k) {
                    acc[k]      = fmaf(w, bf2f(a0[k]), acc[k]);
                    acc[8 + k]  = fmaf(w, bf2f(a1[k]), acc[8 + k]);
                    acc[16 + k] = fmaf(w, bf2f(a2[k]), acc[16 + k]);
                    acc[24 + k] = fmaf(w, bf2f(a3[k]), acc[24 + k]);
                }
            }
        };
        if (inLDS) edges(sCol, sWgt);
        else       edges(col + base, wgt + base);

        #pragma unroll
        for (int q = 0; q < 4; ++q) {
            int kc = g * 4 + q;
            int swz = (kc & ~7) | ((kc & 7) ^ (r & 7));
            bfx8 ov;
            #pragma unroll
            for (int k = 0; k < 8; ++k) ov[k] = (short)f2bf(acc[q * 8 + k]);
            *(bfx8*)(sA + r * LP + swz * 8) = ov;
        }
    }
    __syncthreads();

    // ---- phase 2: MFMA panel loop (B direct from L2) ----
    const int lane = tid & 63;
    const int wave = tid >> 6;
    const int wr = wave >> 1, wc = wave & 1;
    const int l15 = lane & 15, l4 = lane >> 4;
    const int r7 = l15 & 7;
    const int rowA0 = wr * 32 + l15;
    const int gbase = row0 + wr * 32;
    const int koff = l4 * 8;

    #pragma unroll
    for (int p = 0; p < NP; ++p) {
        const int bc0 = p * 64 + wc * 32 + l15;
        f32x4 acc[2][2] = {};
        #pragma unroll
        for (int ks = 0; ks < KP / 32; ++ks) {
            int chunk = l4 + ks * 4;
            int swz = (chunk & ~7) | ((chunk & 7) ^ r7);
            int off = swz * 8;
            bfx8 a0 = *(const bfx8*)(sA + rowA0 * LP + off);
            bfx8 a1 = *(const bfx8*)(sA + (rowA0 + 16) * LP + off);
            bfx8 b0 = {0,0,0,0,0,0,0,0}, b1 = {0,0,0,0,0,0,0,0};
            if (bc0 < CO)      b0 = *(const bfx8*)(BT + (size_t)bc0 * KP + koff + ks * 32);
            if (bc0 + 16 < CO) b1 = *(const bfx8*)(BT + (size_t)(bc0 + 16) * KP + koff + ks * 32);
            acc[0][0] = __builtin_amdgcn_mfma_f32_16x16x32_bf16(a0, b0, acc[0][0], 0, 0, 0);
            acc[0][1] = __builtin_amdgcn_mfma_f32_16x16x32_bf16(a0, b1, acc[0][1], 0, 0, 0);
            acc[1][0] = __builtin_amdgcn_mfma_f32_16x16x32_bf16(a1, b0, acc[1][0], 0, 0, 0);
            acc[1][1] = __builtin_amdgcn_mfma_f32_16x16x32_bf16(a1, b1, acc[1][1], 0, 0, 0);
        }

        // epilogue. D-frag: row = fm*16 + (l>>4)*4 + j, col = fn*16 + (l&15).
        if constexpr (POOL) {
            const bool uni = (batch[gbase] == batch[gbase + 31]);
            #pragma unroll
            for (int fn = 0; fn < 2; ++fn) {
                int cg = p * 64 + wc * 32 + fn * 16 + l15;
                bool cok = cg < CO;
                float bs = cok ? bias[cg] : 0.0f;
                if (uni) {
                    float m = -1e30f;
                    #pragma unroll
                    for (int fm = 0; fm < 2; ++fm)
                        #pragma unroll
                        for (int j = 0; j < 4; ++j)
                            m = fmaxf(m, acc[fm][fn][j]);
                    m = fmaxf(m, __shfl_xor(m, 16));
                    m = fmaxf(m, __shfl_xor(m, 32));
                    if (l4 == 0 && cok) {
                        int g = batch[gbase];
                        float v = fmaxf(m + bs, 0.0f);
                        atomicMax((int*)&pooled[g * CO + cg], __float_as_int(v));
                    }
                } else {
                    #pragma unroll
                    for (int fm = 0; fm < 2; ++fm)
                        #pragma unroll
                        for (int j = 0; j < 4; ++j) {
                            if (cok) {
                                int rg = gbase + fm * 16 + l4 * 4 + j;
                                int g = batch[rg];
                                float v = fmaxf(acc[fm][fn][j] + bs, 0.0f);
                                atomicMax((int*)&pooled[g * CO + cg], __float_as_int(v));
                            }
                        }
                }
            }
        } else {
            #pragma unroll
            for (int fn = 0; fn < 2; ++fn) {
                int cg = p * 64 + wc * 32 + fn * 16 + l15;
                if (cg >= CPO) continue;
                float bs = (cg < CO) ? bias[cg] : 0.0f;
                #pragma unroll
                for (int fm = 0; fm < 2; ++fm)
                    #pragma unroll
                    for (int j = 0; j < 4; ++j) {
                        int row = gbase + fm * 16 + l4 * 4 + j;
                        float v = (cg < CO) ? fmaxf(acc[fm][fn][j] + bs, 0.0f) : 0.0f;
                        hout[(size_t)row * CPO + cg] = f2bf(v);
                    }
            }
        }
    }
}

// ---------------- final FC: out[g][c] = fcb[c] + dot(pooled[g,:], fcW[:,c]) ----------

__global__ __launch_bounds__(256)
void k_fc(const float* __restrict__ pooled, const float* __restrict__ fcW,
          const float* __restrict__ fcb, float* __restrict__ out) {
    __shared__ float sp[8][312];
    const int tid = threadIdx.x;
    const int g0 = blockIdx.x * 8;

    for (int k = tid; k < 8 * 312; k += 256)
        ((float*)sp)[k] = pooled[(size_t)g0 * 312 + k];
    __syncthreads();

    const int half = tid >> 7;       // 0..1 -> graphs g0+half*4 .. +3
    const int c = tid & 127;
    float b = fcb[c];
    float acc0 = b, acc1 = b, acc2 = b, acc3 = b;
    const float* wp = fcW + c;
    const float* p0 = sp[half * 4 + 0];
    const float* p1 = sp[half * 4 + 1];
    const float* p2 = sp[half * 4 + 2];
    const float* p3 = sp[half * 4 + 3];
    #pragma unroll 4
    for (int k = 0; k < 312; ++k) {
        float w = wp[(size_t)k * 128];
        acc0 = fmaf(p0[k], w, acc0);
        acc1 = fmaf(p1[k], w, acc1);
        acc2 = fmaf(p2[k], w, acc2);
        acc3 = fmaf(p3[k], w, acc3);
    }
    float* o = out + (size_t)(g0 + half * 4) * 128 + c;
    o[0] = acc0; o[128] = acc1; o[256] = acc2; o[384] = acc3;
}

// ---------------- launch ----------------

extern "C" void kernel_launch(void* const* d_in, const int* in_sizes, int n_in,
                              void* d_out, int out_size, void* d_ws, size_t ws_size,
                              hipStream_t stream) {
    const float* x    = (const float*)d_in[0];
    const int*   ei   = (const int*)d_in[1];
    const int*   srcv = ei;
    const int*   dstv = ei + NE;
    const int*   batch = (const int*)d_in[2];
    const float* W1 = (const float*)d_in[3];
    const float* b1 = (const float*)d_in[4];
    const float* W2 = (const float*)d_in[5];
    const float* b2 = (const float*)d_in[6];
    const float* W3 = (const float*)d_in[7];
    const float* b3 = (const float*)d_in[8];
    const float* fcW = (const float*)d_in[9];
    const float* fcb = (const float*)d_in[10];
    float* out = (float*)d_out;

    char* ws = (char*)d_ws;
    size_t off = 0;
    auto take = [&](size_t bytes) -> void* {
        void* p = ws + off;
        off += (bytes + 255) & ~(size_t)255;
        return p;
    };
    int*    counts   = (int*)take((size_t)NN * 4);
    int*    rowstart = (int*)take((size_t)(NN + 1) * 4);
    int*    cursor   = (int*)take((size_t)NN * 4);
    float*  dis      = (float*)take((size_t)NN * 4);
    int*    bsum     = (int*)take(512 * 4);
    int*    col      = (int*)take((size_t)NE * 4);
    float*  wgt      = (float*)take((size_t)NE * 4);
    ushort* xb       = (ushort*)take((size_t)NN * 96 * 2);
    ushort* h1       = (ushort*)take((size_t)NN * 96 * 2);
    ushort* h2       = (ushort*)take((size_t)NN * 160 * 2);
    float*  pooled   = (float*)take((size_t)NG * 312 * 4);
    ushort* W1T      = (ushort*)take((size_t)78 * 96 * 2);
    ushort* W2T      = (ushort*)take((size_t)156 * 96 * 2);
    ushort* W3T      = (ushort*)take((size_t)312 * 160 * 2);

    hipMemsetAsync(counts, 0, (size_t)NN * 4, stream);
    hipMemsetAsync(cursor, 0, (size_t)NN * 4, stream);
    hipMemsetAsync(pooled, 0, (size_t)NG * 312 * 4, stream);

    k_count<<<NE / 256, 256, 0, stream>>>(dstv, counts);
    k_dis<<<NN / 256, 256, 0, stream>>>(counts, dis);
    k_scanA<<<NN / 256, 256, 0, stream>>>(counts, rowstart, bsum);
    k_scanB<<<1, 512, 0, stream>>>(bsum);
    k_scanC<<<NN / 256, 256, 0, stream>>>(rowstart, bsum);
    k_fill<<<NE / 256, 256, 0, stream>>>(srcv, dstv, rowstart, cursor, dis, col, wgt);

    k_prepW<78, 78, 96><<<(78 * 96 + 255) / 256, 256, 0, stream>>>(W1, W1T);
    k_prepW<78, 156, 96><<<(156 * 96 + 255) / 256, 256, 0, stream>>>(W2, W2T);
    k_prepW<156, 312, 160><<<(312 * 160 + 255) / 256, 256, 0, stream>>>(W3, W3T);
    k_prepX<<<NN * 96 / 256, 256, 0, stream>>>(x, xb);

    // fused layers: LDS edge staging + 64B-group gather-agg + MFMA GEMM
    k_fused<96, 16, 78, 96, false><<<NN / 64, 256, 0, stream>>>(
        xb, rowstart, col, wgt, dis, W1T, b1, nullptr, h1, nullptr);
    k_fused<96, 16, 156, 160, false><<<NN / 64, 256, 0, stream>>>(
        h1, rowstart, col, wgt, dis, W2T, b2, nullptr, h2, nullptr);
    k_fused<160, 24, 312, 312, true><<<NN / 64, 256, 0, stream>>>(
        h2, rowstart, col, wgt, dis, W3T, b3, batch, nullptr, pooled);

    // FC (fp32, 8 graphs/block, 512 blocks)
    k_fc<<<NG / 8, 256, 0, stream>>>(pooled, fcW, fcb, out);
}

// Round 12
// 339.069 us; speedup vs baseline: 1.0604x; 1.0604x over previous
//
#include <hip/hip_runtime.h>

#define NN 131072   // nodes
#define NE 524288   // edges
#define NG 4096     // graphs

typedef __attribute__((ext_vector_type(8))) short bfx8;
typedef __attribute__((ext_vector_type(4))) float f32x4;

static __device__ __forceinline__ ushort f2bf(float f) {
    union { float f; unsigned u; } v; v.f = f;
    unsigned r = (v.u + 0x7fff + ((v.u >> 16) & 1)) >> 16;   // RNE
    return (ushort)r;
}
static __device__ __forceinline__ float bf2f(short s) {
    union { unsigned u; float f; } v;
    v.u = ((unsigned)(ushort)s) << 16;
    return v.f;
}

// ---------------- preprocessing: degree, dis, CSR ----------------

__global__ void k_count(const int* __restrict__ dst, int* __restrict__ counts) {
    int e = blockIdx.x * blockDim.x + threadIdx.x;
    if (e < NE) atomicAdd(&counts[dst[e]], 1);
}

// exclusive scan of counts (block-level) + per-block sums; also computes dis.
__global__ void k_scanA(const int* __restrict__ in, int* __restrict__ out,
                        int* __restrict__ bsum, float* __restrict__ dis) {
    __shared__ int s[256];
    int t = threadIdx.x;
    int i = blockIdx.x * 256 + t;
    int v = in[i];
    dis[i] = rsqrtf((float)(v + 1));    // +1 self-loop
    s[t] = v;
    __syncthreads();
    for (int off = 1; off < 256; off <<= 1) {
        int x = (t >= off) ? s[t - off] : 0;
        __syncthreads();
        s[t] += x;
        __syncthreads();
    }
    out[i] = s[t] - v;
    if (t == 255) bsum[blockIdx.x] = s[t];
}

__global__ void k_scanB(int* __restrict__ bsum) {
    __shared__ int s[512];
    int t = threadIdx.x;
    int v = bsum[t];
    s[t] = v;
    __syncthreads();
    for (int off = 1; off < 512; off <<= 1) {
        int x = (t >= off) ? s[t - off] : 0;
        __syncthreads();
        s[t] += x;
        __syncthreads();
    }
    bsum[t] = s[t] - v;
}

__global__ void k_scanC(int* __restrict__ rowstart, const int* __restrict__ bsum) {
    int t = threadIdx.x;
    int i = blockIdx.x * 256 + t;
    rowstart[i] += bsum[blockIdx.x];
    if (i == 0) rowstart[NN] = NE;
}

__global__ void k_fill(const int* __restrict__ src, const int* __restrict__ dst,
                       const int* __restrict__ rowstart, int* __restrict__ cursor,
                       const float* __restrict__ dis,
                       int* __restrict__ col, float* __restrict__ wgt) {
    int e = blockIdx.x * blockDim.x + threadIdx.x;
    if (e >= NE) return;
    int s = src[e], d = dst[e];
    int pos = rowstart[d] + atomicAdd(&cursor[d], 1);
    col[pos] = s;
    wgt[pos] = dis[s] * dis[d];
}

// merged prep: xb = pad(bf16(x)); WkT = bf16(Wk^T) zero-padded K.
__global__ void k_prep(const float* __restrict__ x, ushort* __restrict__ xb,
                       const float* __restrict__ W1, ushort* __restrict__ W1T,
                       const float* __restrict__ W2, ushort* __restrict__ W2T,
                       const float* __restrict__ W3, ushort* __restrict__ W3T) {
    int idx = blockIdx.x * 256 + threadIdx.x;
    const int NX = NN * 96;
    if (idx < NX) {
        int i = idx / 96, c = idx - i * 96;
        xb[idx] = (c < 78) ? f2bf(x[i * 78 + c]) : (ushort)0;
        return;
    }
    idx -= NX;
    if (idx < 78 * 96) {                       // W1T [78][96], CI=78
        int n = idx / 96, k = idx - n * 96;
        W1T[idx] = (k < 78) ? f2bf(W1[k * 78 + n]) : (ushort)0;
        return;
    }
    idx -= 78 * 96;
    if (idx < 156 * 96) {                      // W2T [156][96], CI=78
        int n = idx / 96, k = idx - n * 96;
        W2T[idx] = (k < 78) ? f2bf(W2[k * 156 + n]) : (ushort)0;
        return;
    }
    idx -= 156 * 96;
    if (idx < 312 * 160) {                     // W3T [312][160], CI=156
        int n = idx / 160, k = idx - n * 160;
        W3T[idx] = (k < 156) ? f2bf(W3[k * 312 + n]) : (ushort)0;
    }
}

// ---------------- fused layer: gather-agg into LDS, then MFMA GEMM ----------------
// Phase 1: block's 64 node-rows of A aggregated straight into XOR-swizzled sA.
//          unit = (row, 16B chunk); adjacent lanes share the src row -> coalesced.
// Phase 2: panel-loop MFMA, B read directly from L2 (weights tiny), no barriers.

template<int KP, int LCH, int CO, int CPO, bool POOL>
__global__ __launch_bounds__(256)
void k_fused(const ushort* __restrict__ hin, const int* __restrict__ rowstart,
             const int* __restrict__ col, const float* __restrict__ wgt,
             const float* __restrict__ dis,
             const ushort* __restrict__ BT, const float* __restrict__ bias,
             const int* __restrict__ batch,
             ushort* __restrict__ hout, float* __restrict__ pooled) {
    constexpr int NCH = KP / 8;           // 16B chunks per row
    constexpr int LP  = LCH * 8;          // LDS row pitch in bf16 elems
    constexpr int NP  = (CO + 63) / 64;   // 64-col panels
    __shared__ ushort sA[64 * LP];

    const int tid  = threadIdx.x;
    const int row0 = blockIdx.x * 64;

    // ---- phase 1: gather-aggregate into sA ----
    for (int id = tid; id < 64 * NCH; id += 256) {
        int r  = id / NCH, kc = id - r * NCH;
        int i  = row0 + r;
        int ch = kc * 8;
        const ushort* gb = hin + ch;

        float d = dis[i];
        bfx8 self = *(const bfx8*)(hin + (size_t)i * KP + ch);
        float acc[8];
        #pragma unroll
        for (int k = 0; k < 8; ++k) acc[k] = d * d * bf2f(self[k]);

        int j = rowstart[i], j1 = rowstart[i + 1];
        for (; j + 4 <= j1; j += 4) {
            int c0 = col[j], c1 = col[j + 1], c2 = col[j + 2], c3 = col[j + 3];
            float w0 = wgt[j], w1 = wgt[j + 1], w2 = wgt[j + 2], w3 = wgt[j + 3];
            bfx8 g0 = *(const bfx8*)(gb + (size_t)c0 * KP);
            bfx8 g1 = *(const bfx8*)(gb + (size_t)c1 * KP);
            bfx8 g2 = *(const bfx8*)(gb + (size_t)c2 * KP);
            bfx8 g3 = *(const bfx8*)(gb + (size_t)c3 * KP);
            #pragma unroll
            for (int k = 0; k < 8; ++k) {
                acc[k] = fmaf(w0, bf2f(g0[k]), acc[k]);
                acc[k] = fmaf(w1, bf2f(g1[k]), acc[k]);
                acc[k] = fmaf(w2, bf2f(g2[k]), acc[k]);
                acc[k] = fmaf(w3, bf2f(g3[k]), acc[k]);
            }
        }
        for (; j < j1; ++j) {
            int c = col[j];
            float w = wgt[j];
            bfx8 g = *(const bfx8*)(gb + (size_t)c * KP);
            #pragma unroll
            for (int k = 0; k < 8; ++k) acc[k] = fmaf(w, bf2f(g[k]), acc[k]);
        }

        bfx8 ov;
        #pragma unroll
        for (int k = 0; k < 8; ++k) ov[k] = (short)f2bf(acc[k]);
        int swz = (kc & ~7) | ((kc & 7) ^ (r & 7));
        *(bfx8*)(sA + r * LP + swz * 8) = ov;
    }
    __syncthreads();

    // ---- phase 2: MFMA panel loop (B direct from L2) ----
    const int lane = tid & 63;
    const int wave = tid >> 6;
    const int wr = wave >> 1, wc = wave & 1;
    const int l15 = lane & 15, l4 = lane >> 4;
    const int r7 = l15 & 7;
    const int rowA0 = wr * 32 + l15;
    const int gbase = row0 + wr * 32;
    const int koff = l4 * 8;

    #pragma unroll
    for (int p = 0; p < NP; ++p) {
        const int bc0 = p * 64 + wc * 32 + l15;
        f32x4 acc[2][2] = {};
        #pragma unroll
        for (int ks = 0; ks < KP / 32; ++ks) {
            int chunk = l4 + ks * 4;
            int swz = (chunk & ~7) | ((chunk & 7) ^ r7);
            int off = swz * 8;
            bfx8 a0 = *(const bfx8*)(sA + rowA0 * LP + off);
            bfx8 a1 = *(const bfx8*)(sA + (rowA0 + 16) * LP + off);
            bfx8 b0 = {0,0,0,0,0,0,0,0}, b1 = {0,0,0,0,0,0,0,0};
            if (bc0 < CO)      b0 = *(const bfx8*)(BT + (size_t)bc0 * KP + koff + ks * 32);
            if (bc0 + 16 < CO) b1 = *(const bfx8*)(BT + (size_t)(bc0 + 16) * KP + koff + ks * 32);
            acc[0][0] = __builtin_amdgcn_mfma_f32_16x16x32_bf16(a0, b0, acc[0][0], 0, 0, 0);
            acc[0][1] = __builtin_amdgcn_mfma_f32_16x16x32_bf16(a0, b1, acc[0][1], 0, 0, 0);
            acc[1][0] = __builtin_amdgcn_mfma_f32_16x16x32_bf16(a1, b0, acc[1][0], 0, 0, 0);
            acc[1][1] = __builtin_amdgcn_mfma_f32_16x16x32_bf16(a1, b1, acc[1][1], 0, 0, 0);
        }

        // epilogue. D-frag: row = fm*16 + (l>>4)*4 + j, col = fn*16 + (l&15).
        if constexpr (POOL) {
            const bool uni = (batch[gbase] == batch[gbase + 31]);
            #pragma unroll
            for (int fn = 0; fn < 2; ++fn) {
                int cg = p * 64 + wc * 32 + fn * 16 + l15;
                bool cok = cg < CO;
                float bs = cok ? bias[cg] : 0.0f;
                if (uni) {
                    float m = -1e30f;
                    #pragma unroll
                    for (int fm = 0; fm < 2; ++fm)
                        #pragma unroll
                        for (int j = 0; j < 4; ++j)
                            m = fmaxf(m, acc[fm][fn][j]);
                    m = fmaxf(m, __shfl_xor(m, 16));
                    m = fmaxf(m, __shfl_xor(m, 32));
                    if (l4 == 0 && cok) {
                        int g = batch[gbase];
                        float v = fmaxf(m + bs, 0.0f);
                        atomicMax((int*)&pooled[g * CO + cg], __float_as_int(v));
                    }
                } else {
                    #pragma unroll
                    for (int fm = 0; fm < 2; ++fm)
                        #pragma unroll
                        for (int j = 0; j < 4; ++j) {
                            if (cok) {
                                int rg = gbase + fm * 16 + l4 * 4 + j;
                                int g = batch[rg];
                                float v = fmaxf(acc[fm][fn][j] + bs, 0.0f);
                                atomicMax((int*)&pooled[g * CO + cg], __float_as_int(v));
                            }
                        }
                }
            }
        } else {
            #pragma unroll
            for (int fn = 0; fn < 2; ++fn) {
                int cg = p * 64 + wc * 32 + fn * 16 + l15;
                if (cg >= CPO) continue;
                float bs = (cg < CO) ? bias[cg] : 0.0f;
                #pragma unroll
                for (int fm = 0; fm < 2; ++fm)
                    #pragma unroll
                    for (int j = 0; j < 4; ++j) {
                        int row = gbase + fm * 16 + l4 * 4 + j;
                        float v = (cg < CO) ? fmaxf(acc[fm][fn][j] + bs, 0.0f) : 0.0f;
                        hout[(size_t)row * CPO + cg] = f2bf(v);
                    }
            }
        }
    }
}

// ---------------- final FC: out[g][c] = fcb[c] + dot(pooled[g,:], fcW[:,c]) ----------

__global__ __launch_bounds__(256)
void k_fc(const float* __restrict__ pooled, const float* __restrict__ fcW,
          const float* __restrict__ fcb, float* __restrict__ out) {
    __shared__ float sp[8][312];
    const int tid = threadIdx.x;
    const int g0 = blockIdx.x * 8;

    for (int k = tid; k < 8 * 312; k += 256)
        ((float*)sp)[k] = pooled[(size_t)g0 * 312 + k];
    __syncthreads();

    const int half = tid >> 7;       // 0..1 -> graphs g0+half*4 .. +3
    const int c = tid & 127;
    float b = fcb[c];
    float acc0 = b, acc1 = b, acc2 = b, acc3 = b;
    const float* wp = fcW + c;
    const float* p0 = sp[half * 4 + 0];
    const float* p1 = sp[half * 4 + 1];
    const float* p2 = sp[half * 4 + 2];
    const float* p3 = sp[half * 4 + 3];
    #pragma unroll 4
    for (int k = 0; k < 312; ++k) {
        float w = wp[(size_t)k * 128];
        acc0 = fmaf(p0[k], w, acc0);
        acc1 = fmaf(p1[k], w, acc1);
        acc2 = fmaf(p2[k], w, acc2);
        acc3 = fmaf(p3[k], w, acc3);
    }
    float* o = out + (size_t)(g0 + half * 4) * 128 + c;
    o[0] = acc0; o[128] = acc1; o[256] = acc2; o[384] = acc3;
}

// ---------------- launch ----------------

extern "C" void kernel_launch(void* const* d_in, const int* in_sizes, int n_in,
                              void* d_out, int out_size, void* d_ws, size_t ws_size,
                              hipStream_t stream) {
    const float* x    = (const float*)d_in[0];
    const int*   ei   = (const int*)d_in[1];
    const int*   srcv = ei;
    const int*   dstv = ei + NE;
    const int*   batch = (const int*)d_in[2];
    const float* W1 = (const float*)d_in[3];
    const float* b1 = (const float*)d_in[4];
    const float* W2 = (const float*)d_in[5];
    const float* b2 = (const float*)d_in[6];
    const float* W3 = (const float*)d_in[7];
    const float* b3 = (const float*)d_in[8];
    const float* fcW = (const float*)d_in[9];
    const float* fcb = (const float*)d_in[10];
    float* out = (float*)d_out;

    char* ws = (char*)d_ws;
    size_t off = 0;
    auto take = [&](size_t bytes) -> void* {
        void* p = ws + off;
        off += (bytes + 255) & ~(size_t)255;
        return p;
    };
    // counts/cursor/pooled contiguous -> one memset
    int*    counts   = (int*)take((size_t)NN * 4);
    int*    cursor   = (int*)take((size_t)NN * 4);
    float*  pooled   = (float*)take((size_t)NG * 312 * 4);
    int*    rowstart = (int*)take((size_t)(NN + 1) * 4);
    float*  dis      = (float*)take((size_t)NN * 4);
    int*    bsum     = (int*)take(512 * 4);
    int*    col      = (int*)take((size_t)NE * 4);
    float*  wgt      = (float*)take((size_t)NE * 4);
    ushort* xb       = (ushort*)take((size_t)NN * 96 * 2);
    ushort* h1       = (ushort*)take((size_t)NN * 96 * 2);
    ushort* h2       = (ushort*)take((size_t)NN * 160 * 2);
    ushort* W1T      = (ushort*)take((size_t)78 * 96 * 2);
    ushort* W2T      = (ushort*)take((size_t)156 * 96 * 2);
    ushort* W3T      = (ushort*)take((size_t)312 * 160 * 2);

    hipMemsetAsync(counts, 0, (size_t)NN * 4 + (size_t)NN * 4 + (size_t)NG * 312 * 4, stream);

    const int PREP_TOTAL = NN * 96 + 78 * 96 + 156 * 96 + 312 * 160;
    k_prep<<<(PREP_TOTAL + 255) / 256, 256, 0, stream>>>(x, xb, W1, W1T, W2, W2T, W3, W3T);

    k_count<<<NE / 256, 256, 0, stream>>>(dstv, counts);
    k_scanA<<<NN / 256, 256, 0, stream>>>(counts, rowstart, bsum, dis);
    k_scanB<<<1, 512, 0, stream>>>(bsum);
    k_scanC<<<NN / 256, 256, 0, stream>>>(rowstart, bsum);
    k_fill<<<NE / 256, 256, 0, stream>>>(srcv, dstv, rowstart, cursor, dis, col, wgt);

    // fused layers: gather-agg (phase 1) + MFMA GEMM (phase 2)
    k_fused<96, 16, 78, 96, false><<<NN / 64, 256, 0, stream>>>(
        xb, rowstart, col, wgt, dis, W1T, b1, nullptr, h1, nullptr);
    k_fused<96, 16, 156, 160, false><<<NN / 64, 256, 0, stream>>>(
        h1, rowstart, col, wgt, dis, W2T, b2, nullptr, h2, nullptr);
    k_fused<160, 24, 312, 312, true><<<NN / 64, 256, 0, stream>>>(
        h2, rowstart, col, wgt, dis, W3T, b3, batch, nullptr, pooled);

    // FC (fp32, 8 graphs/block, 512 blocks)
    k_fc<<<NG / 8, 256, 0, stream>>>(pooled, fcW, fcb, out);
}